// Round 15
// baseline (327.091 us; speedup 1.0000x reference)
//
#include <hip/hip_runtime.h>

// Problem constants
#define B_ 8
#define N_ 2000
#define D_ 480          // NH*C = 30*16
#define L_ 8
#define K_ 4096
#define T1_ 6

#define BM 64
#define BN 96

typedef __attribute__((ext_vector_type(4))) float f32x4;
typedef __attribute__((ext_vector_type(8))) short bf16x8;

__device__ __forceinline__ unsigned short f2bf(float f) {
    unsigned int u = __builtin_bit_cast(unsigned int, f);
    u += 0x7fffu + ((u >> 16) & 1u);   // RNE
    return (unsigned short)(u >> 16);
}
__device__ __forceinline__ float bf2f(unsigned short u) {
    return __builtin_bit_cast(float, ((unsigned int)u) << 16);
}

// global -> LDS direct DMA, 16B per lane (wave-uniform LDS base + lane*16)
#define GLL16(g, l)                                                        \
    __builtin_amdgcn_global_load_lds(                                      \
        (const __attribute__((address_space(1))) void*)(g),                \
        (__attribute__((address_space(3))) void*)(l), 16, 0, 0)

__device__ __forceinline__ void vm0()  { asm volatile("s_waitcnt vmcnt(0)" ::: "memory"); }
__device__ __forceinline__ void vm4()  { asm volatile("s_waitcnt vmcnt(4)" ::: "memory"); }
__device__ __forceinline__ void vm5()  { asm volatile("s_waitcnt vmcnt(5)" ::: "memory"); }
__device__ __forceinline__ void vm8()  { asm volatile("s_waitcnt vmcnt(8)" ::: "memory"); }
__device__ __forceinline__ void vm10() { asm volatile("s_waitcnt vmcnt(10)" ::: "memory"); }

// ---------------------------------------------------------------------------
__global__ __launch_bounds__(256)
void k_flag(const unsigned char* __restrict__ raw, int* flag) {
    int t = threadIdx.x;
    if (t == 0) *flag = 0;
    __syncthreads();
    int any = 0;
    for (int i = t; i < 4096; i += 256) {
        if ((i & 3) != 0 && raw[i] != 0) any = 1;
    }
    if (__any(any) && (t & 63) == 0) atomicOr(flag, 1);
}

__global__ void k_wconv(const float* __restrict__ w,
                        unsigned short* __restrict__ wbf) {
    int i = blockIdx.x * blockDim.x + threadIdx.x;
    if (i < D_ * D_) wbf[i] = f2bf(w[i]);
}

__global__ void k_feats2bf(const float* __restrict__ f,
                           unsigned short* __restrict__ o) {
    int i = blockIdx.x * blockDim.x + threadIdx.x;
    if (i < B_ * N_ * D_ / 4) {
        float4 v = ((const float4*)f)[i];
        ushort4 u;
        u.x = f2bf(v.x); u.y = f2bf(v.y); u.z = f2bf(v.z); u.w = f2bf(v.w);
        ((ushort4*)o)[i] = u;
    }
}

__global__ void k_zero_idx(int* __restrict__ counts, int* __restrict__ cursor) {
    int i = blockIdx.x * blockDim.x + threadIdx.x;
    if (i < B_ * N_) { counts[i] = 0; cursor[i] = 0; }
}

__global__ void k_endcounts(const unsigned char* __restrict__ raw,
                            const int* __restrict__ flag,
                            const int* __restrict__ seg,
                            int* __restrict__ endi, int* __restrict__ counts) {
    int i = blockIdx.x * blockDim.x + threadIdx.x;
    if (i >= B_ * L_ * K_) return;
    int e = (*flag) ? (int)raw[i] : ((const int*)raw)[i];
    e = (e != 0) ? 1 : 0;
    endi[i] = e;
    if (e) {
        int b = i / (L_ * K_);
        atomicAdd(&counts[b * N_ + seg[i]], 1);
    }
}

__global__ __launch_bounds__(256)
void k_scan(const int* __restrict__ counts, int* __restrict__ offsets) {
    __shared__ int part[256];
    const int CH = 63;
    int t = threadIdx.x;
    int s = 0;
    for (int j = 0; j < CH; ++j) {
        int i = t * CH + j;
        if (i < B_ * N_) s += counts[i];
    }
    part[t] = s;
    __syncthreads();
    if (t == 0) {
        int run = 0;
        for (int i = 0; i < 256; ++i) { int v = part[i]; part[i] = run; run += v; }
    }
    __syncthreads();
    int run = part[t];
    for (int j = 0; j < CH; ++j) {
        int i = t * CH + j;
        if (i < B_ * N_) { offsets[i] = run; run += counts[i]; }
    }
    if (t == 255) offsets[B_ * N_] = run;
}

__global__ void k_build(const int* __restrict__ endi,
                        const int* __restrict__ seg,
                        const int* __restrict__ offsets,
                        int* __restrict__ cursor, int* __restrict__ nodelist) {
    int i = blockIdx.x * blockDim.x + threadIdx.x;
    if (i >= B_ * L_ * K_) return;
    if (!endi[i]) return;
    int b = i / (L_ * K_);
    int lk = i - b * (L_ * K_);
    int n = seg[i];
    int pos = atomicAdd(&cursor[b * N_ + n], 1);
    nodelist[offsets[b * N_ + n] + pos] = lk;
}

// ---------------------------------------------------------------------------
// Level l>=1: r12's LDS-minimized GEMM (best measured: 34us/rep probe,
// ~287us end-to-end).  256 thr = 4 waves (2Mx2N), wave tile 64x80 = 4x5
// frags, acc=80 VGPR.  gll staging with source-side XOR swizzle
// (bank-conflict-free: 2.5e7 -> 0 measured r12), 4-buffer depth-2 pipeline,
// issue-first order: issue gll(s+2) -> wait vm(2 batches) -> barrier ->
// ds_read -> MFMA.  (r13 reorder and r14 512-thread variants both measured
// worse: 45us/rep and +20us total respectively.)
__global__ __launch_bounds__(256, 2)
void k_level_gemm(const float* __restrict__ attn,
                  const int* __restrict__ seg, const int* __restrict__ parent,
                  const unsigned short* __restrict__ featsbf,
                  const unsigned short* __restrict__ wb,
                  const unsigned short* __restrict__ zprev,
                  unsigned short* __restrict__ zcur,
                  int l, int prevRows, int useps) {
    __shared__ unsigned short AsF[4 * 128 * 32];   // 4 bufs x 8KB
    __shared__ unsigned short BsF[4 * 160 * 32];   // 4 bufs x 10KB
    __shared__ int gidx_s[128], seg_s[128];
    __shared__ float alpha_s[128];

    int tid = threadIdx.x;
    int id = blockIdx.x;                 // 768 = 8 batches x 32 M x 3 N
    int b = id & 7;
    int within = id >> 3;
    int mb = within / 3, nb = within - mb * 3;
    int k0 = mb * 128, d0 = nb * 160;

    if (tid < 128) {
        int base = (b * L_ + l) * K_;
        int p = parent[base + k0 + tid];
        int sk = seg[base + k0 + tid];
        int ps = seg[base - K_ + p];
        gidx_s[tid] = useps ? ps : p;
        seg_s[tid] = sk;
        alpha_s[tid] = attn[((size_t)b * N_ + ps) * N_ + sk];
    }
    __syncthreads();

    const unsigned short* zb = zprev + (size_t)b * prevRows * D_;
    int w = tid >> 6, lane = tid & 63;
    int l4 = lane >> 2, c4 = lane & 3;

    const unsigned short* srcA[2];
    int dA[2];
#pragma unroll
    for (int j = 0; j < 2; ++j) {
        int r = (w * 2 + j) * 16 + l4;
        int sc = c4 ^ ((r >> 1) & 3);          // source-side swizzle
        srcA[j] = zb + (size_t)gidx_s[r] * D_ + sc * 8;
        dA[j] = (w * 2 + j) * 512;
    }
    int nB = (w < 2) ? 3 : 2;
    const unsigned short* srcB[3];
    int dB[3];
#pragma unroll
    for (int t = 0; t < 3; ++t) {
        int jb = w + t * 4;
        if (jb > 9) jb = 9;                    // unused (never issued)
        int r = jb * 16 + l4;
        int sc = c4 ^ ((r >> 1) & 3);
        srcB[t] = wb + (size_t)(d0 + r) * D_ + sc * 8;
        dB[t] = jb * 512;
    }

    int waveM = w >> 1, waveN = w & 1;
    int lr = lane & 15, kg = lane >> 4;
    int afo[4], bfo[5];
#pragma unroll
    for (int fm = 0; fm < 4; ++fm) {
        int r = waveM * 64 + fm * 16 + lr;
        afo[fm] = r * 32 + (kg ^ ((r >> 1) & 3)) * 8;   // inverse swizzle
    }
#pragma unroll
    for (int fn = 0; fn < 5; ++fn) {
        int r = waveN * 80 + fn * 16 + lr;
        bfo[fn] = r * 32 + (kg ^ ((r >> 1) & 3)) * 8;
    }

    f32x4 acc[4][5];
#pragma unroll
    for (int fm = 0; fm < 4; ++fm)
#pragma unroll
        for (int fn = 0; fn < 5; ++fn) acc[fm][fn] = (f32x4)0.f;

    // prologue: issue batches 0,1 into bufs 0,1
#pragma unroll
    for (int q = 0; q < 2; ++q) {
#pragma unroll
        for (int j = 0; j < 2; ++j)
            GLL16(srcA[j] + q * 32, &AsF[q * 4096 + dA[j]]);
#pragma unroll
        for (int t = 0; t < 3; ++t)
            if (t < nB) GLL16(srcB[t] + q * 32, &BsF[q * 5120 + dB[t]]);
    }

#pragma unroll
    for (int s = 0; s < 15; ++s) {
        // issue batch s+2 into buf (s+2)&3 (readers were 2 barriers back)
        if (s + 2 <= 14) {
            int q2 = (s + 2) & 3;
#pragma unroll
            for (int j = 0; j < 2; ++j)
                GLL16(srcA[j] + (s + 2) * 32, &AsF[q2 * 4096 + dA[j]]);
#pragma unroll
            for (int t = 0; t < 3; ++t)
                if (t < nB) GLL16(srcB[t] + (s + 2) * 32, &BsF[q2 * 5120 + dB[t]]);
        }
        // counted wait: batch s landed; batches s+1, s+2 stay in flight
        if (s <= 12)      { if (w < 2) vm10(); else vm8(); }
        else if (s == 13) { if (w < 2) vm5();  else vm4(); }
        else              vm0();
        __builtin_amdgcn_s_barrier();
        __builtin_amdgcn_sched_barrier(0);

        int q = s & 3;
        bf16x8 af[4], bfr[5];
#pragma unroll
        for (int fm = 0; fm < 4; ++fm)
            af[fm] = *(const bf16x8*)&AsF[q * 4096 + afo[fm]];
#pragma unroll
        for (int fn = 0; fn < 5; ++fn)
            bfr[fn] = *(const bf16x8*)&BsF[q * 5120 + bfo[fn]];
#pragma unroll
        for (int fm = 0; fm < 4; ++fm)
#pragma unroll
            for (int fn = 0; fn < 5; ++fn)
                acc[fm][fn] = __builtin_amdgcn_mfma_f32_16x16x32_bf16(
                    af[fm], bfr[fn], acc[fm][fn], 0, 0, 0);
    }

    // epilogue: C layout col=lane&15, row=(lane>>4)*4+j
#pragma unroll
    for (int fm = 0; fm < 4; ++fm) {
#pragma unroll
        for (int j = 0; j < 4; ++j) {
            int rl = waveM * 64 + fm * 16 + kg * 4 + j;
            float al = alpha_s[rl];
            int sk = seg_s[rl];
            const unsigned short* hrow = featsbf + ((size_t)b * N_ + sk) * D_;
            unsigned short* zrow = zcur + ((size_t)b * K_ + k0 + rl) * D_;
#pragma unroll
            for (int fn = 0; fn < 5; ++fn) {
                int c = d0 + waveN * 80 + fn * 16 + lr;
                zrow[c] = f2bf(al * acc[fm][fn][j] + bf2f(hrow[c]));
            }
        }
    }
}

// Fused gather-reduce + mean + predictor + mask. One wave per (b,n).
__global__ __launch_bounds__(64)
void k_final_gather(const unsigned short* __restrict__ featsbf,
                    const unsigned short* __restrict__ zall,
                    const int* __restrict__ offsets,
                    const int* __restrict__ nodelist,
                    const float* __restrict__ Wpred,
                    const float* __restrict__ bpred, float* __restrict__ out) {
    int bn = blockIdx.x;
    int b = bn / N_;
    int s0 = offsets[bn], s1 = offsets[bn + 1];
    int cnt = s1 - s0;
    int lane = threadIdx.x;

    float acc[2][4] = {{0, 0, 0, 0}, {0, 0, 0, 0}};
    const unsigned short* ownrow = featsbf + (size_t)bn * D_;

    for (int s = s0; s < s1; ++s) {
        int e = nodelist[s];
        int l = e >> 12, k = e & (K_ - 1);
        const unsigned short* row =
            (l == 0) ? ownrow
                     : zall + (((size_t)(l - 1) * B_ + b) * K_ + k) * D_;
#pragma unroll
        for (int it = 0; it < 2; ++it) {
            int c4 = lane + 64 * it;
            if (c4 < D_ / 4) {
                ushort4 u = *(const ushort4*)(row + c4 * 4);
                acc[it][0] += bf2f(u.x);
                acc[it][1] += bf2f(u.y);
                acc[it][2] += bf2f(u.z);
                acc[it][3] += bf2f(u.w);
            }
        }
    }

    float inv = 1.f / (float)(cnt > 1 ? cnt : 1);
    float m[2][4];
#pragma unroll
    for (int it = 0; it < 2; ++it)
#pragma unroll
        for (int j = 0; j < 4; ++j) m[it][j] = acc[it][j] * inv;

    float* outz = out + (size_t)B_ * N_ * T1_ + (size_t)bn * D_;
#pragma unroll
    for (int it = 0; it < 2; ++it) {
        int c4 = lane + 64 * it;
        if (c4 < D_ / 4) {
            float4 v;
            v.x = m[it][0]; v.y = m[it][1]; v.z = m[it][2]; v.w = m[it][3];
            *(float4*)(outz + c4 * 4) = v;
        }
    }

    float part[T1_] = {0, 0, 0, 0, 0, 0};
#pragma unroll
    for (int it = 0; it < 2; ++it) {
        int c4 = lane + 64 * it;
        if (c4 < D_ / 4) {
#pragma unroll
            for (int t = 0; t < T1_; ++t)
#pragma unroll
                for (int j = 0; j < 4; ++j)
                    part[t] += m[it][j] * Wpred[t * D_ + c4 * 4 + j];
        }
    }
#pragma unroll
    for (int t = 0; t < T1_; ++t) {
        float v = part[t];
        for (int off = 32; off; off >>= 1) v += __shfl_down(v, off);
        if (lane == 0)
            out[(size_t)bn * T1_ + t] = (cnt > 0) ? (v + bpred[t]) : 0.f;
    }
    if (lane == 0)
        out[(size_t)B_ * N_ * T1_ + (size_t)B_ * N_ * D_ + bn] =
            (cnt > 0) ? 1.f : 0.f;
}

// ======================= fallback (atomic) path kernels =====================
__global__ void k_zero(float* __restrict__ sums, int* __restrict__ counts) {
    int stride = gridDim.x * blockDim.x;
    int i0 = blockIdx.x * blockDim.x + threadIdx.x;
    for (int i = i0; i < B_ * N_ * D_; i += stride) sums[i] = 0.f;
    for (int i = i0; i < B_ * N_; i += stride) counts[i] = 0;
}

__global__ __launch_bounds__(128)
void k_level0_at(const float* __restrict__ feats, const int* __restrict__ seg,
                 const int* __restrict__ endi, unsigned short* __restrict__ z0,
                 float* __restrict__ sums) {
    int bk = blockIdx.x;
    int b = bk >> 12;
    int k = bk & (K_ - 1);
    int sidx = (b * L_ + 0) * K_ + k;
    int n = seg[sidx];
    int e = endi[sidx];
    const float* src = feats + ((size_t)b * N_ + n) * D_;
    unsigned short* dst = z0 + ((size_t)b * K_ + k) * D_;
    float* sm = sums + ((size_t)b * N_ + n) * D_;
    int t = threadIdx.x;
    if (t < D_ / 4) {
        float4 v = *(const float4*)(src + t * 4);
        ushort4 o;
        o.x = f2bf(v.x); o.y = f2bf(v.y); o.z = f2bf(v.z); o.w = f2bf(v.w);
        *(ushort4*)(dst + t * 4) = o;
        if (e) {
            atomicAdd(&sm[t * 4 + 0], v.x);
            atomicAdd(&sm[t * 4 + 1], v.y);
            atomicAdd(&sm[t * 4 + 2], v.z);
            atomicAdd(&sm[t * 4 + 3], v.w);
        }
    }
}

__global__ __launch_bounds__(256)
void k_level_mfma_at(const float* __restrict__ feats,
                     const float* __restrict__ attn,
                     const int* __restrict__ seg, const int* __restrict__ parent,
                     const int* __restrict__ endi,
                     const unsigned short* __restrict__ wb,
                     const unsigned short* __restrict__ zprev,
                     unsigned short* __restrict__ zcur,
                     float* __restrict__ sums, int l, int storez) {
    __shared__ int par_s[BM], seg_s[BM], end_s[BM];
    __shared__ float alpha_s[BM];
    int b = blockIdx.z;
    int k0 = blockIdx.x * BM;
    int d0 = blockIdx.y * BN;
    int tid = threadIdx.x;
    if (tid < BM) {
        int base = (b * L_ + l) * K_;
        int p = parent[base + k0 + tid];
        int sk = seg[base + k0 + tid];
        int ps = seg[base - K_ + p];
        par_s[tid] = p; seg_s[tid] = sk;
        end_s[tid] = endi[base + k0 + tid];
        alpha_s[tid] = attn[((size_t)b * N_ + ps) * N_ + sk];
    }
    __syncthreads();
    int wave = tid >> 6, lane = tid & 63;
    int wr0 = (wave >> 1) * 32, wc0 = (wave & 1) * 48;
    int laneRow = lane & 15, laneK = (lane >> 4) * 8;
    const unsigned short* zb = zprev + (size_t)b * K_ * D_;
    const unsigned short* arow[2];
#pragma unroll
    for (int mi = 0; mi < 2; ++mi)
        arow[mi] = zb + (size_t)par_s[wr0 + mi * 16 + laneRow] * D_ + laneK;
    const unsigned short* brow[3];
#pragma unroll
    for (int ni = 0; ni < 3; ++ni)
        brow[ni] = wb + (size_t)(d0 + wc0 + ni * 16 + laneRow) * D_ + laneK;
    f32x4 acc[2][3];
#pragma unroll
    for (int mi = 0; mi < 2; ++mi)
#pragma unroll
        for (int ni = 0; ni < 3; ++ni) acc[mi][ni] = (f32x4)0.f;
    bf16x8 af[2], bfr[3];
#pragma unroll
    for (int mi = 0; mi < 2; ++mi) af[mi] = *(const bf16x8*)(arow[mi]);
#pragma unroll
    for (int ni = 0; ni < 3; ++ni) bfr[ni] = *(const bf16x8*)(brow[ni]);
#pragma unroll
    for (int e0 = 0; e0 < D_; e0 += 32) {
        bf16x8 an[2], bn[3];
        if (e0 + 32 < D_) {
#pragma unroll
            for (int mi = 0; mi < 2; ++mi) an[mi] = *(const bf16x8*)(arow[mi] + e0 + 32);
#pragma unroll
            for (int ni = 0; ni < 3; ++ni) bn[ni] = *(const bf16x8*)(brow[ni] + e0 + 32);
        }
#pragma unroll
        for (int mi = 0; mi < 2; ++mi)
#pragma unroll
            for (int ni = 0; ni < 3; ++ni)
                acc[mi][ni] = __builtin_amdgcn_mfma_f32_16x16x32_bf16(
                    af[mi], bfr[ni], acc[mi][ni], 0, 0, 0);
        if (e0 + 32 < D_) {
#pragma unroll
            for (int mi = 0; mi < 2; ++mi) af[mi] = an[mi];
#pragma unroll
            for (int ni = 0; ni < 3; ++ni) bfr[ni] = bn[ni];
        }
    }
#pragma unroll
    for (int mi = 0; mi < 2; ++mi) {
#pragma unroll
        for (int j = 0; j < 4; ++j) {
            int rl = wr0 + mi * 16 + (lane >> 4) * 4 + j;
            int k = k0 + rl;
            float al = alpha_s[rl];
            int sk = seg_s[rl];
            int en = end_s[rl];
            const float* hrow = feats + ((size_t)b * N_ + sk) * D_;
            unsigned short* zrow = zcur + ((size_t)b * K_ + k) * D_;
            float* srow = sums + ((size_t)b * N_ + sk) * D_;
#pragma unroll
            for (int ni = 0; ni < 3; ++ni) {
                int c = d0 + wc0 + ni * 16 + (lane & 15);
                float v = al * acc[mi][ni][j] + hrow[c];
                if (storez) zrow[c] = f2bf(v);
                if (en) atomicAdd(&srow[c], v);
            }
        }
    }
}

__global__ __launch_bounds__(64)
void k_final_at(const float* __restrict__ sums, const int* __restrict__ counts,
                const float* __restrict__ Wpred, const float* __restrict__ bpred,
                float* __restrict__ out) {
    int bn = blockIdx.x;
    int cnt = counts[bn];
    float inv = 1.f / (float)(cnt > 1 ? cnt : 1);
    int lane = threadIdx.x;
    const float* srow = sums + (size_t)bn * D_;
    float* zout = out + (size_t)B_ * N_ * T1_ + (size_t)bn * D_;
    float part[T1_] = {0, 0, 0, 0, 0, 0};
    for (int d = lane; d < D_; d += 64) {
        float mval = srow[d] * inv;
        zout[d] = mval;
#pragma unroll
        for (int t = 0; t < T1_; ++t) part[t] += mval * Wpred[t * D_ + d];
    }
#pragma unroll
    for (int t = 0; t < T1_; ++t) {
        float v = part[t];
        for (int off = 32; off; off >>= 1) v += __shfl_down(v, off);
        if (lane == 0)
            out[(size_t)bn * T1_ + t] = (cnt > 0) ? (v + bpred[t]) : 0.f;
    }
    if (lane == 0)
        out[(size_t)B_ * N_ * T1_ + (size_t)B_ * N_ * D_ + bn] =
            (cnt > 0) ? 1.f : 0.f;
}

// ===========================================================================
extern "C" void kernel_launch(void* const* d_in, const int* in_sizes, int n_in,
                              void* d_out, int out_size, void* d_ws,
                              size_t ws_size, hipStream_t stream) {
    const float* feats = (const float*)d_in[0];
    const float* attn  = (const float*)d_in[1];
    const int*   seg   = (const int*)d_in[2];
    const int*   par   = (const int*)d_in[3];
    const unsigned char* isend_raw = (const unsigned char*)d_in[4];
    const float* Wproj = (const float*)d_in[5];
    const float* Wpred = (const float*)d_in[6];
    const float* bpred = (const float*)d_in[7];

    char* p = (char*)d_ws;
    auto carve = [&p](size_t bytes) -> char* {
        char* r = p;
        p += (bytes + 255) & ~(size_t)255;
        return r;
    };

    size_t need = 0;
    {
        size_t q = 0;
        auto sz = [&q](size_t b) { q += (b + 255) & ~(size_t)255; };
        sz(B_ * N_ * 4);
        sz(B_ * N_ * 4);
        sz((B_ * N_ + 1) * 4);
        sz((size_t)B_ * L_ * K_ * 4);
        sz(16);
        sz((size_t)B_ * L_ * K_ * 4);
        sz((size_t)B_ * N_ * D_ * 2);
        sz((size_t)D_ * D_ * 2);
        sz((size_t)(L_ - 1) * B_ * K_ * D_ * 2);
        need = q;
    }

    if (ws_size >= need) {
        int* counts = (int*)carve(B_ * N_ * 4);
        int* cursor = (int*)carve(B_ * N_ * 4);
        int* offsets = (int*)carve((B_ * N_ + 1) * 4);
        int* endi = (int*)carve((size_t)B_ * L_ * K_ * 4);
        int* flag = (int*)carve(16);
        int* nodelist = (int*)carve((size_t)B_ * L_ * K_ * 4);
        unsigned short* featsbf = (unsigned short*)carve((size_t)B_ * N_ * D_ * 2);
        unsigned short* wbf = (unsigned short*)carve((size_t)D_ * D_ * 2);
        unsigned short* zall =
            (unsigned short*)carve((size_t)(L_ - 1) * B_ * K_ * D_ * 2);

        k_flag<<<1, 256, 0, stream>>>(isend_raw, flag);
        k_zero_idx<<<(B_ * N_ + 255) / 256, 256, 0, stream>>>(counts, cursor);
        k_wconv<<<(D_ * D_ + 255) / 256, 256, 0, stream>>>(Wproj, wbf);
        k_feats2bf<<<(B_ * N_ * D_ / 4 + 255) / 256, 256, 0, stream>>>(feats,
                                                                       featsbf);
        k_endcounts<<<(B_ * L_ * K_ + 255) / 256, 256, 0, stream>>>(
            isend_raw, flag, seg, endi, counts);
        k_scan<<<1, 256, 0, stream>>>(counts, offsets);
        k_build<<<(B_ * L_ * K_ + 255) / 256, 256, 0, stream>>>(
            endi, seg, offsets, cursor, nodelist);

        for (int l = 1; l < L_; ++l) {
            const unsigned short* zp =
                (l == 1) ? featsbf : zall + (size_t)(l - 2) * B_ * K_ * D_;
            unsigned short* zc = zall + (size_t)(l - 1) * B_ * K_ * D_;
            k_level_gemm<<<768, 256, 0, stream>>>(
                attn, seg, par, featsbf, wbf, zp, zc, l,
                (l == 1) ? N_ : K_, (l == 1) ? 1 : 0);
        }

        k_final_gather<<<B_ * N_, 64, 0, stream>>>(
            featsbf, zall, offsets, nodelist, Wpred, bpred, (float*)d_out);
    } else {
        // fallback: round-3 atomic path
        float* sums = (float*)carve((size_t)B_ * N_ * D_ * 4);
        int* counts = (int*)carve(B_ * N_ * 4);
        int* endi = (int*)carve((size_t)B_ * L_ * K_ * 4);
        int* flag = (int*)carve(16);
        unsigned short* z0bf = (unsigned short*)carve((size_t)B_ * K_ * D_ * 2);
        unsigned short* z1bf = (unsigned short*)carve((size_t)B_ * K_ * D_ * 2);
        unsigned short* wbf = (unsigned short*)carve((size_t)D_ * D_ * 2);

        k_flag<<<1, 256, 0, stream>>>(isend_raw, flag);
        k_zero<<<1024, 256, 0, stream>>>(sums, counts);
        k_wconv<<<(D_ * D_ + 255) / 256, 256, 0, stream>>>(Wproj, wbf);
        k_endcounts<<<(B_ * L_ * K_ + 255) / 256, 256, 0, stream>>>(
            isend_raw, flag, seg, endi, counts);
        k_level0_at<<<B_ * K_, 128, 0, stream>>>(feats, seg, endi, z0bf, sums);
        unsigned short* zp = z0bf;
        unsigned short* zc = z1bf;
        for (int l = 1; l < L_; ++l) {
            k_level_mfma_at<<<dim3(K_ / BM, D_ / BN, B_), 256, 0, stream>>>(
                feats, attn, seg, par, endi, wbf, zp, zc, sums, l,
                (l < L_ - 1) ? 1 : 0);
            unsigned short* t = zp; zp = zc; zc = t;
        }
        k_final_at<<<B_ * N_, 64, 0, stream>>>(sums, counts, Wpred, bpred,
                                               (float*)d_out);
    }
}

// Round 16
// 308.803 us; speedup vs baseline: 1.0592x; 1.0592x over previous
//
#include <hip/hip_runtime.h>

// Problem constants
#define B_ 8
#define N_ 2000
#define D_ 480          // NH*C = 30*16
#define L_ 8
#define K_ 4096
#define T1_ 6

#define BM 64
#define BN 96

typedef __attribute__((ext_vector_type(4))) float f32x4;
typedef __attribute__((ext_vector_type(8))) short bf16x8;

__device__ __forceinline__ unsigned short f2bf(float f) {
    unsigned int u = __builtin_bit_cast(unsigned int, f);
    u += 0x7fffu + ((u >> 16) & 1u);   // RNE
    return (unsigned short)(u >> 16);
}
__device__ __forceinline__ float bf2f(unsigned short u) {
    return __builtin_bit_cast(float, ((unsigned int)u) << 16);
}

// global -> LDS direct DMA, 16B per lane (wave-uniform LDS base + lane*16)
#define GLL16(g, l)                                                        \
    __builtin_amdgcn_global_load_lds(                                      \
        (const __attribute__((address_space(1))) void*)(g),                \
        (__attribute__((address_space(3))) void*)(l), 16, 0, 0)

__device__ __forceinline__ void vm0() { asm volatile("s_waitcnt vmcnt(0)" ::: "memory"); }
__device__ __forceinline__ void vm2() { asm volatile("s_waitcnt vmcnt(2)" ::: "memory"); }
__device__ __forceinline__ void vm3() { asm volatile("s_waitcnt vmcnt(3)" ::: "memory"); }
__device__ __forceinline__ void vm4() { asm volatile("s_waitcnt vmcnt(4)" ::: "memory"); }
__device__ __forceinline__ void vm6() { asm volatile("s_waitcnt vmcnt(6)" ::: "memory"); }

// ---------------------------------------------------------------------------
__global__ __launch_bounds__(256)
void k_flag(const unsigned char* __restrict__ raw, int* flag) {
    int t = threadIdx.x;
    if (t == 0) *flag = 0;
    __syncthreads();
    int any = 0;
    for (int i = t; i < 4096; i += 256) {
        if ((i & 3) != 0 && raw[i] != 0) any = 1;
    }
    if (__any(any) && (t & 63) == 0) atomicOr(flag, 1);
}

__global__ void k_wconv(const float* __restrict__ w,
                        unsigned short* __restrict__ wbf) {
    int i = blockIdx.x * blockDim.x + threadIdx.x;
    if (i < D_ * D_) wbf[i] = f2bf(w[i]);
}

__global__ void k_feats2bf(const float* __restrict__ f,
                           unsigned short* __restrict__ o) {
    int i = blockIdx.x * blockDim.x + threadIdx.x;
    if (i < B_ * N_ * D_ / 4) {
        float4 v = ((const float4*)f)[i];
        ushort4 u;
        u.x = f2bf(v.x); u.y = f2bf(v.y); u.z = f2bf(v.z); u.w = f2bf(v.w);
        ((ushort4*)o)[i] = u;
    }
}

__global__ void k_zero_idx(int* __restrict__ counts, int* __restrict__ cursor) {
    int i = blockIdx.x * blockDim.x + threadIdx.x;
    if (i < B_ * N_) { counts[i] = 0; cursor[i] = 0; }
}

__global__ void k_endcounts(const unsigned char* __restrict__ raw,
                            const int* __restrict__ flag,
                            const int* __restrict__ seg,
                            int* __restrict__ endi, int* __restrict__ counts) {
    int i = blockIdx.x * blockDim.x + threadIdx.x;
    if (i >= B_ * L_ * K_) return;
    int e = (*flag) ? (int)raw[i] : ((const int*)raw)[i];
    e = (e != 0) ? 1 : 0;
    endi[i] = e;
    if (e) {
        int b = i / (L_ * K_);
        atomicAdd(&counts[b * N_ + seg[i]], 1);
    }
}

__global__ __launch_bounds__(256)
void k_scan(const int* __restrict__ counts, int* __restrict__ offsets) {
    __shared__ int part[256];
    const int CH = 63;
    int t = threadIdx.x;
    int s = 0;
    for (int j = 0; j < CH; ++j) {
        int i = t * CH + j;
        if (i < B_ * N_) s += counts[i];
    }
    part[t] = s;
    __syncthreads();
    if (t == 0) {
        int run = 0;
        for (int i = 0; i < 256; ++i) { int v = part[i]; part[i] = run; run += v; }
    }
    __syncthreads();
    int run = part[t];
    for (int j = 0; j < CH; ++j) {
        int i = t * CH + j;
        if (i < B_ * N_) { offsets[i] = run; run += counts[i]; }
    }
    if (t == 255) offsets[B_ * N_] = run;
}

__global__ void k_build(const int* __restrict__ endi,
                        const int* __restrict__ seg,
                        const int* __restrict__ offsets,
                        int* __restrict__ cursor, int* __restrict__ nodelist) {
    int i = blockIdx.x * blockDim.x + threadIdx.x;
    if (i >= B_ * L_ * K_) return;
    if (!endi[i]) return;
    int b = i / (L_ * K_);
    int lk = i - b * (L_ * K_);
    int n = seg[i];
    int pos = atomicAdd(&cursor[b * N_ + n], 1);
    nodelist[offsets[b * N_ + n] + pos] = lk;
}

// ---------------------------------------------------------------------------
// Level l>=1: best-measured configuration (r14, 308.9us end-to-end direct).
// Z_l = diag(alpha)*(Z_{l-1}[gidx] @ W^T) + H_l.
// 512 thr = 8 waves (4M x 2N), wave tile 32x80 = 2x5 frags, acc=40 VGPR.
// gll staging with source-side XOR swizzle (bank-conflict-free, r12: 2.5e7->0),
// 4-buffer depth-2 pipeline, issue-first order: issue gll(s+2) -> wait
// vm(2 batches) -> barrier -> ds_read -> MFMA.  16 waves/CU: the two
// resident blocks cover each other's barrier stalls per-SIMD.
// (Direct no-probe measurements: this=308.9us; 256-thr variant=327.1;
//  r10 triple-buf=324.5; r13 wait-first reorder=worse. Keep this.)
__global__ __launch_bounds__(512, 4)
void k_level_gemm(const float* __restrict__ attn,
                  const int* __restrict__ seg, const int* __restrict__ parent,
                  const unsigned short* __restrict__ featsbf,
                  const unsigned short* __restrict__ wb,
                  const unsigned short* __restrict__ zprev,
                  unsigned short* __restrict__ zcur,
                  int l, int prevRows, int useps) {
    __shared__ unsigned short AsF[4 * 128 * 32];   // 4 bufs x 8KB
    __shared__ unsigned short BsF[4 * 160 * 32];   // 4 bufs x 10KB
    __shared__ int gidx_s[128], seg_s[128];
    __shared__ float alpha_s[128];

    int tid = threadIdx.x;
    int id = blockIdx.x;                 // 768 = 8 batches x 32 M x 3 N
    int b = id & 7;
    int within = id >> 3;
    int mb = within / 3, nb = within - mb * 3;
    int k0 = mb * 128, d0 = nb * 160;

    if (tid < 128) {
        int base = (b * L_ + l) * K_;
        int p = parent[base + k0 + tid];
        int sk = seg[base + k0 + tid];
        int ps = seg[base - K_ + p];
        gidx_s[tid] = useps ? ps : p;
        seg_s[tid] = sk;
        alpha_s[tid] = attn[((size_t)b * N_ + ps) * N_ + sk];
    }
    __syncthreads();

    const unsigned short* zb = zprev + (size_t)b * prevRows * D_;
    int w = tid >> 6, lane = tid & 63;
    int l4 = lane >> 2, c4 = lane & 3;

    // A: wave w stages chunk w (rows w*16..w*16+15); 1 gll/batch
    const unsigned short* srcA;
    int dA;
    {
        int r = w * 16 + l4;
        int sc = c4 ^ ((r >> 1) & 3);          // source-side swizzle
        srcA = zb + (size_t)gidx_s[r] * D_ + sc * 8;
        dA = w * 512;
    }
    // B: wave w stages chunk w; waves 0,1 additionally chunks 8,9
    int nB = (w < 2) ? 2 : 1;
    const unsigned short* srcB[2];
    int dB[2];
#pragma unroll
    for (int t = 0; t < 2; ++t) {
        int jb = (t == 0) ? w : (8 + w);
        if (jb > 9) jb = 9;                    // unused (never issued)
        int r = jb * 16 + l4;
        int sc = c4 ^ ((r >> 1) & 3);
        srcB[t] = wb + (size_t)(d0 + r) * D_ + sc * 8;
        dB[t] = jb * 512;
    }

    int waveM = w >> 1, waveN = w & 1;         // 4M x 2N
    int lr = lane & 15, kg = lane >> 4;
    int afo[2], bfo[5];
#pragma unroll
    for (int fm = 0; fm < 2; ++fm) {
        int r = waveM * 32 + fm * 16 + lr;
        afo[fm] = r * 32 + (kg ^ ((r >> 1) & 3)) * 8;   // inverse swizzle
    }
#pragma unroll
    for (int fn = 0; fn < 5; ++fn) {
        int r = waveN * 80 + fn * 16 + lr;
        bfo[fn] = r * 32 + (kg ^ ((r >> 1) & 3)) * 8;
    }

    f32x4 acc[2][5];
#pragma unroll
    for (int fm = 0; fm < 2; ++fm)
#pragma unroll
        for (int fn = 0; fn < 5; ++fn) acc[fm][fn] = (f32x4)0.f;

    // prologue: issue batches 0,1 into bufs 0,1
#pragma unroll
    for (int q = 0; q < 2; ++q) {
        GLL16(srcA + q * 32, &AsF[q * 4096 + dA]);
#pragma unroll
        for (int t = 0; t < 2; ++t)
            if (t < nB) GLL16(srcB[t] + q * 32, &BsF[q * 5120 + dB[t]]);
    }

#pragma unroll
    for (int s = 0; s < 15; ++s) {
        // issue batch s+2 first (buf (s+2)&3: readers were 2 barriers back)
        if (s + 2 <= 14) {
            int q2 = (s + 2) & 3;
            GLL16(srcA + (s + 2) * 32, &AsF[q2 * 4096 + dA]);
#pragma unroll
            for (int t = 0; t < 2; ++t)
                if (t < nB) GLL16(srcB[t] + (s + 2) * 32, &BsF[q2 * 5120 + dB[t]]);
        }
        // wait: batch s landed, batches s+1,s+2 stay in flight
        if (s <= 12)      { if (w < 2) vm6(); else vm4(); }
        else if (s == 13) { if (w < 2) vm3(); else vm2(); }
        else              vm0();
        __builtin_amdgcn_s_barrier();

        int q = s & 3;
        bf16x8 af[2], bfr[5];
#pragma unroll
        for (int fm = 0; fm < 2; ++fm)
            af[fm] = *(const bf16x8*)&AsF[q * 4096 + afo[fm]];
#pragma unroll
        for (int fn = 0; fn < 5; ++fn)
            bfr[fn] = *(const bf16x8*)&BsF[q * 5120 + bfo[fn]];
#pragma unroll
        for (int fm = 0; fm < 2; ++fm)
#pragma unroll
            for (int fn = 0; fn < 5; ++fn)
                acc[fm][fn] = __builtin_amdgcn_mfma_f32_16x16x32_bf16(
                    af[fm], bfr[fn], acc[fm][fn], 0, 0, 0);
    }

    // epilogue: C layout col=lane&15, row=(lane>>4)*4+j
#pragma unroll
    for (int fm = 0; fm < 2; ++fm) {
#pragma unroll
        for (int j = 0; j < 4; ++j) {
            int rl = waveM * 32 + fm * 16 + kg * 4 + j;
            float al = alpha_s[rl];
            int sk = seg_s[rl];
            const unsigned short* hrow = featsbf + ((size_t)b * N_ + sk) * D_;
            unsigned short* zrow = zcur + ((size_t)b * K_ + k0 + rl) * D_;
#pragma unroll
            for (int fn = 0; fn < 5; ++fn) {
                int c = d0 + waveN * 80 + fn * 16 + lr;
                zrow[c] = f2bf(al * acc[fm][fn][j] + bf2f(hrow[c]));
            }
        }
    }
}

// Fused gather-reduce + mean + predictor + mask. One wave per (b,n).
__global__ __launch_bounds__(64)
void k_final_gather(const unsigned short* __restrict__ featsbf,
                    const unsigned short* __restrict__ zall,
                    const int* __restrict__ offsets,
                    const int* __restrict__ nodelist,
                    const float* __restrict__ Wpred,
                    const float* __restrict__ bpred, float* __restrict__ out) {
    int bn = blockIdx.x;
    int b = bn / N_;
    int s0 = offsets[bn], s1 = offsets[bn + 1];
    int cnt = s1 - s0;
    int lane = threadIdx.x;

    float acc[2][4] = {{0, 0, 0, 0}, {0, 0, 0, 0}};
    const unsigned short* ownrow = featsbf + (size_t)bn * D_;

    for (int s = s0; s < s1; ++s) {
        int e = nodelist[s];
        int l = e >> 12, k = e & (K_ - 1);
        const unsigned short* row =
            (l == 0) ? ownrow
                     : zall + (((size_t)(l - 1) * B_ + b) * K_ + k) * D_;
#pragma unroll
        for (int it = 0; it < 2; ++it) {
            int c4 = lane + 64 * it;
            if (c4 < D_ / 4) {
                ushort4 u = *(const ushort4*)(row + c4 * 4);
                acc[it][0] += bf2f(u.x);
                acc[it][1] += bf2f(u.y);
                acc[it][2] += bf2f(u.z);
                acc[it][3] += bf2f(u.w);
            }
        }
    }

    float inv = 1.f / (float)(cnt > 1 ? cnt : 1);
    float m[2][4];
#pragma unroll
    for (int it = 0; it < 2; ++it)
#pragma unroll
        for (int j = 0; j < 4; ++j) m[it][j] = acc[it][j] * inv;

    float* outz = out + (size_t)B_ * N_ * T1_ + (size_t)bn * D_;
#pragma unroll
    for (int it = 0; it < 2; ++it) {
        int c4 = lane + 64 * it;
        if (c4 < D_ / 4) {
            float4 v;
            v.x = m[it][0]; v.y = m[it][1]; v.z = m[it][2]; v.w = m[it][3];
            *(float4*)(outz + c4 * 4) = v;
        }
    }

    float part[T1_] = {0, 0, 0, 0, 0, 0};
#pragma unroll
    for (int it = 0; it < 2; ++it) {
        int c4 = lane + 64 * it;
        if (c4 < D_ / 4) {
#pragma unroll
            for (int t = 0; t < T1_; ++t)
#pragma unroll
                for (int j = 0; j < 4; ++j)
                    part[t] += m[it][j] * Wpred[t * D_ + c4 * 4 + j];
        }
    }
#pragma unroll
    for (int t = 0; t < T1_; ++t) {
        float v = part[t];
        for (int off = 32; off; off >>= 1) v += __shfl_down(v, off);
        if (lane == 0)
            out[(size_t)bn * T1_ + t] = (cnt > 0) ? (v + bpred[t]) : 0.f;
    }
    if (lane == 0)
        out[(size_t)B_ * N_ * T1_ + (size_t)B_ * N_ * D_ + bn] =
            (cnt > 0) ? 1.f : 0.f;
}

// ======================= fallback (atomic) path kernels =====================
__global__ void k_zero(float* __restrict__ sums, int* __restrict__ counts) {
    int stride = gridDim.x * blockDim.x;
    int i0 = blockIdx.x * blockDim.x + threadIdx.x;
    for (int i = i0; i < B_ * N_ * D_; i += stride) sums[i] = 0.f;
    for (int i = i0; i < B_ * N_; i += stride) counts[i] = 0;
}

__global__ __launch_bounds__(128)
void k_level0_at(const float* __restrict__ feats, const int* __restrict__ seg,
                 const int* __restrict__ endi, unsigned short* __restrict__ z0,
                 float* __restrict__ sums) {
    int bk = blockIdx.x;
    int b = bk >> 12;
    int k = bk & (K_ - 1);
    int sidx = (b * L_ + 0) * K_ + k;
    int n = seg[sidx];
    int e = endi[sidx];
    const float* src = feats + ((size_t)b * N_ + n) * D_;
    unsigned short* dst = z0 + ((size_t)b * K_ + k) * D_;
    float* sm = sums + ((size_t)b * N_ + n) * D_;
    int t = threadIdx.x;
    if (t < D_ / 4) {
        float4 v = *(const float4*)(src + t * 4);
        ushort4 o;
        o.x = f2bf(v.x); o.y = f2bf(v.y); o.z = f2bf(v.z); o.w = f2bf(v.w);
        *(ushort4*)(dst + t * 4) = o;
        if (e) {
            atomicAdd(&sm[t * 4 + 0], v.x);
            atomicAdd(&sm[t * 4 + 1], v.y);
            atomicAdd(&sm[t * 4 + 2], v.z);
            atomicAdd(&sm[t * 4 + 3], v.w);
        }
    }
}

__global__ __launch_bounds__(256)
void k_level_mfma_at(const float* __restrict__ feats,
                     const float* __restrict__ attn,
                     const int* __restrict__ seg, const int* __restrict__ parent,
                     const int* __restrict__ endi,
                     const unsigned short* __restrict__ wb,
                     const unsigned short* __restrict__ zprev,
                     unsigned short* __restrict__ zcur,
                     float* __restrict__ sums, int l, int storez) {
    __shared__ int par_s[BM], seg_s[BM], end_s[BM];
    __shared__ float alpha_s[BM];
    int b = blockIdx.z;
    int k0 = blockIdx.x * BM;
    int d0 = blockIdx.y * BN;
    int tid = threadIdx.x;
    if (tid < BM) {
        int base = (b * L_ + l) * K_;
        int p = parent[base + k0 + tid];
        int sk = seg[base + k0 + tid];
        int ps = seg[base - K_ + p];
        par_s[tid] = p; seg_s[tid] = sk;
        end_s[tid] = endi[base + k0 + tid];
        alpha_s[tid] = attn[((size_t)b * N_ + ps) * N_ + sk];
    }
    __syncthreads();
    int wave = tid >> 6, lane = tid & 63;
    int wr0 = (wave >> 1) * 32, wc0 = (wave & 1) * 48;
    int laneRow = lane & 15, laneK = (lane >> 4) * 8;
    const unsigned short* zb = zprev + (size_t)b * K_ * D_;
    const unsigned short* arow[2];
#pragma unroll
    for (int mi = 0; mi < 2; ++mi)
        arow[mi] = zb + (size_t)par_s[wr0 + mi * 16 + laneRow] * D_ + laneK;
    const unsigned short* brow[3];
#pragma unroll
    for (int ni = 0; ni < 3; ++ni)
        brow[ni] = wb + (size_t)(d0 + wc0 + ni * 16 + laneRow) * D_ + laneK;
    f32x4 acc[2][3];
#pragma unroll
    for (int mi = 0; mi < 2; ++mi)
#pragma unroll
        for (int ni = 0; ni < 3; ++ni) acc[mi][ni] = (f32x4)0.f;
    bf16x8 af[2], bfr[3];
#pragma unroll
    for (int mi = 0; mi < 2; ++mi) af[mi] = *(const bf16x8*)(arow[mi]);
#pragma unroll
    for (int ni = 0; ni < 3; ++ni) bfr[ni] = *(const bf16x8*)(brow[ni]);
#pragma unroll
    for (int e0 = 0; e0 < D_; e0 += 32) {
        bf16x8 an[2], bn[3];
        if (e0 + 32 < D_) {
#pragma unroll
            for (int mi = 0; mi < 2; ++mi) an[mi] = *(const bf16x8*)(arow[mi] + e0 + 32);
#pragma unroll
            for (int ni = 0; ni < 3; ++ni) bn[ni] = *(const bf16x8*)(brow[ni] + e0 + 32);
        }
#pragma unroll
        for (int mi = 0; mi < 2; ++mi)
#pragma unroll
            for (int ni = 0; ni < 3; ++ni)
                acc[mi][ni] = __builtin_amdgcn_mfma_f32_16x16x32_bf16(
                    af[mi], bfr[ni], acc[mi][ni], 0, 0, 0);
        if (e0 + 32 < D_) {
#pragma unroll
            for (int mi = 0; mi < 2; ++mi) af[mi] = an[mi];
#pragma unroll
            for (int ni = 0; ni < 3; ++ni) bfr[ni] = bn[ni];
        }
    }
#pragma unroll
    for (int mi = 0; mi < 2; ++mi) {
#pragma unroll
        for (int j = 0; j < 4; ++j) {
            int rl = wr0 + mi * 16 + (lane >> 4) * 4 + j;
            int k = k0 + rl;
            float al = alpha_s[rl];
            int sk = seg_s[rl];
            int en = end_s[rl];
            const float* hrow = feats + ((size_t)b * N_ + sk) * D_;
            unsigned short* zrow = zcur + ((size_t)b * K_ + k) * D_;
            float* srow = sums + ((size_t)b * N_ + sk) * D_;
#pragma unroll
            for (int ni = 0; ni < 3; ++ni) {
                int c = d0 + wc0 + ni * 16 + (lane & 15);
                float v = al * acc[mi][ni][j] + hrow[c];
                if (storez) zrow[c] = f2bf(v);
                if (en) atomicAdd(&srow[c], v);
            }
        }
    }
}

__global__ __launch_bounds__(64)
void k_final_at(const float* __restrict__ sums, const int* __restrict__ counts,
                const float* __restrict__ Wpred, const float* __restrict__ bpred,
                float* __restrict__ out) {
    int bn = blockIdx.x;
    int cnt = counts[bn];
    float inv = 1.f / (float)(cnt > 1 ? cnt : 1);
    int lane = threadIdx.x;
    const float* srow = sums + (size_t)bn * D_;
    float* zout = out + (size_t)B_ * N_ * T1_ + (size_t)bn * D_;
    float part[T1_] = {0, 0, 0, 0, 0, 0};
    for (int d = lane; d < D_; d += 64) {
        float mval = srow[d] * inv;
        zout[d] = mval;
#pragma unroll
        for (int t = 0; t < T1_; ++t) part[t] += mval * Wpred[t * D_ + d];
    }
#pragma unroll
    for (int t = 0; t < T1_; ++t) {
        float v = part[t];
        for (int off = 32; off; off >>= 1) v += __shfl_down(v, off);
        if (lane == 0)
            out[(size_t)bn * T1_ + t] = (cnt > 0) ? (v + bpred[t]) : 0.f;
    }
    if (lane == 0)
        out[(size_t)B_ * N_ * T1_ + (size_t)B_ * N_ * D_ + bn] =
            (cnt > 0) ? 1.f : 0.f;
}

// ===========================================================================
extern "C" void kernel_launch(void* const* d_in, const int* in_sizes, int n_in,
                              void* d_out, int out_size, void* d_ws,
                              size_t ws_size, hipStream_t stream) {
    const float* feats = (const float*)d_in[0];
    const float* attn  = (const float*)d_in[1];
    const int*   seg   = (const int*)d_in[2];
    const int*   par   = (const int*)d_in[3];
    const unsigned char* isend_raw = (const unsigned char*)d_in[4];
    const float* Wproj = (const float*)d_in[5];
    const float* Wpred = (const float*)d_in[6];
    const float* bpred = (const float*)d_in[7];

    char* p = (char*)d_ws;
    auto carve = [&p](size_t bytes) -> char* {
        char* r = p;
        p += (bytes + 255) & ~(size_t)255;
        return r;
    };

    size_t need = 0;
    {
        size_t q = 0;
        auto sz = [&q](size_t b) { q += (b + 255) & ~(size_t)255; };
        sz(B_ * N_ * 4);
        sz(B_ * N_ * 4);
        sz((B_ * N_ + 1) * 4);
        sz((size_t)B_ * L_ * K_ * 4);
        sz(16);
        sz((size_t)B_ * L_ * K_ * 4);
        sz((size_t)B_ * N_ * D_ * 2);
        sz((size_t)D_ * D_ * 2);
        sz((size_t)(L_ - 1) * B_ * K_ * D_ * 2);
        need = q;
    }

    if (ws_size >= need) {
        int* counts = (int*)carve(B_ * N_ * 4);
        int* cursor = (int*)carve(B_ * N_ * 4);
        int* offsets = (int*)carve((B_ * N_ + 1) * 4);
        int* endi = (int*)carve((size_t)B_ * L_ * K_ * 4);
        int* flag = (int*)carve(16);
        int* nodelist = (int*)carve((size_t)B_ * L_ * K_ * 4);
        unsigned short* featsbf = (unsigned short*)carve((size_t)B_ * N_ * D_ * 2);
        unsigned short* wbf = (unsigned short*)carve((size_t)D_ * D_ * 2);
        unsigned short* zall =
            (unsigned short*)carve((size_t)(L_ - 1) * B_ * K_ * D_ * 2);

        k_flag<<<1, 256, 0, stream>>>(isend_raw, flag);
        k_zero_idx<<<(B_ * N_ + 255) / 256, 256, 0, stream>>>(counts, cursor);
        k_wconv<<<(D_ * D_ + 255) / 256, 256, 0, stream>>>(Wproj, wbf);
        k_feats2bf<<<(B_ * N_ * D_ / 4 + 255) / 256, 256, 0, stream>>>(feats,
                                                                       featsbf);
        k_endcounts<<<(B_ * L_ * K_ + 255) / 256, 256, 0, stream>>>(
            isend_raw, flag, seg, endi, counts);
        k_scan<<<1, 256, 0, stream>>>(counts, offsets);
        k_build<<<(B_ * L_ * K_ + 255) / 256, 256, 0, stream>>>(
            endi, seg, offsets, cursor, nodelist);

        for (int l = 1; l < L_; ++l) {
            const unsigned short* zp =
                (l == 1) ? featsbf : zall + (size_t)(l - 2) * B_ * K_ * D_;
            unsigned short* zc = zall + (size_t)(l - 1) * B_ * K_ * D_;
            k_level_gemm<<<768, 512, 0, stream>>>(
                attn, seg, par, featsbf, wbf, zp, zc, l,
                (l == 1) ? N_ : K_, (l == 1) ? 1 : 0);
        }

        k_final_gather<<<B_ * N_, 64, 0, stream>>>(
            featsbf, zall, offsets, nodelist, Wpred, bpred, (float*)d_out);
    } else {
        // fallback: round-3 atomic path
        float* sums = (float*)carve((size_t)B_ * N_ * D_ * 4);
        int* counts = (int*)carve(B_ * N_ * 4);
        int* endi = (int*)carve((size_t)B_ * L_ * K_ * 4);
        int* flag = (int*)carve(16);
        unsigned short* z0bf = (unsigned short*)carve((size_t)B_ * K_ * D_ * 2);
        unsigned short* z1bf = (unsigned short*)carve((size_t)B_ * K_ * D_ * 2);
        unsigned short* wbf = (unsigned short*)carve((size_t)D_ * D_ * 2);

        k_flag<<<1, 256, 0, stream>>>(isend_raw, flag);
        k_zero<<<1024, 256, 0, stream>>>(sums, counts);
        k_wconv<<<(D_ * D_ + 255) / 256, 256, 0, stream>>>(Wproj, wbf);
        k_endcounts<<<(B_ * L_ * K_ + 255) / 256, 256, 0, stream>>>(
            isend_raw, flag, seg, endi, counts);
        k_level0_at<<<B_ * K_, 128, 0, stream>>>(feats, seg, endi, z0bf, sums);
        unsigned short* zp = z0bf;
        unsigned short* zc = z1bf;
        for (int l = 1; l < L_; ++l) {
            k_level_mfma_at<<<dim3(K_ / BM, D_ / BN, B_), 256, 0, stream>>>(
                feats, attn, seg, par, endi, wbf, zp, zc, sums, l,
                (l < L_ - 1) ? 1 : 0);
            unsigned short* t = zp; zp = zc; zc = t;
        }
        k_final_at<<<B_ * N_, 64, 0, stream>>>(sums, counts, Wpred, bpred,
                                               (float*)d_out);
    }
}

// Round 17
// 307.157 us; speedup vs baseline: 1.0649x; 1.0054x over previous
//
#include <hip/hip_runtime.h>

// Problem constants
#define B_ 8
#define N_ 2000
#define D_ 480          // NH*C = 30*16
#define L_ 8
#define K_ 4096
#define T1_ 6

#define BM 64
#define BN 96

typedef __attribute__((ext_vector_type(4))) float f32x4;
typedef __attribute__((ext_vector_type(8))) short bf16x8;

__device__ __forceinline__ unsigned short f2bf(float f) {
    unsigned int u = __builtin_bit_cast(unsigned int, f);
    u += 0x7fffu + ((u >> 16) & 1u);   // RNE
    return (unsigned short)(u >> 16);
}
__device__ __forceinline__ float bf2f(unsigned short u) {
    return __builtin_bit_cast(float, ((unsigned int)u) << 16);
}

// global -> LDS direct DMA, 16B per lane (wave-uniform LDS base + lane*16)
#define GLL16(g, l)                                                        \
    __builtin_amdgcn_global_load_lds(                                      \
        (const __attribute__((address_space(1))) void*)(g),                \
        (__attribute__((address_space(3))) void*)(l), 16, 0, 0)

__device__ __forceinline__ void vm0() { asm volatile("s_waitcnt vmcnt(0)" ::: "memory"); }
__device__ __forceinline__ void vm2() { asm volatile("s_waitcnt vmcnt(2)" ::: "memory"); }
__device__ __forceinline__ void vm3() { asm volatile("s_waitcnt vmcnt(3)" ::: "memory"); }
__device__ __forceinline__ void vm4() { asm volatile("s_waitcnt vmcnt(4)" ::: "memory"); }
__device__ __forceinline__ void vm6() { asm volatile("s_waitcnt vmcnt(6)" ::: "memory"); }

// ---------------------------------------------------------------------------
// Fused: zero counts/cursor (all blocks) + is_end dtype sniff (block 0).
// sniff: 1 => 1-byte bool, 0 => int32 (bytes %4!=0 all zero for 0/1 ints).
__global__ __launch_bounds__(256)
void k_prep(const unsigned char* __restrict__ raw, int* __restrict__ flag,
            int* __restrict__ counts, int* __restrict__ cursor) {
    int i = blockIdx.x * blockDim.x + threadIdx.x;
    if (i < B_ * N_) { counts[i] = 0; cursor[i] = 0; }
    if (blockIdx.x == 0) {
        int t = threadIdx.x;
        if (t == 0) *flag = 0;
        __syncthreads();
        int any = 0;
        for (int j = t; j < 4096; j += 256)
            if ((j & 3) != 0 && raw[j] != 0) any = 1;
        if (__any(any) && (t & 63) == 0) atomicOr(flag, 1);
    }
}

// Fused: W_proj f32->bf16 + feats f32->bf16
__global__ void k_conv(const float* __restrict__ w,
                       unsigned short* __restrict__ wbf,
                       const float* __restrict__ f,
                       unsigned short* __restrict__ o) {
    int i = blockIdx.x * blockDim.x + threadIdx.x;
    if (i < D_ * D_) wbf[i] = f2bf(w[i]);
    if (i < B_ * N_ * D_ / 4) {
        float4 v = ((const float4*)f)[i];
        ushort4 u;
        u.x = f2bf(v.x); u.y = f2bf(v.y); u.z = f2bf(v.z); u.w = f2bf(v.w);
        ((ushort4*)o)[i] = u;
    }
}

__global__ void k_endcounts(const unsigned char* __restrict__ raw,
                            const int* __restrict__ flag,
                            const int* __restrict__ seg,
                            int* __restrict__ endi, int* __restrict__ counts) {
    int i = blockIdx.x * blockDim.x + threadIdx.x;
    if (i >= B_ * L_ * K_) return;
    int e = (*flag) ? (int)raw[i] : ((const int*)raw)[i];
    e = (e != 0) ? 1 : 0;
    endi[i] = e;
    if (e) {
        int b = i / (L_ * K_);
        atomicAdd(&counts[b * N_ + seg[i]], 1);
    }
}

__global__ __launch_bounds__(256)
void k_scan(const int* __restrict__ counts, int* __restrict__ offsets) {
    __shared__ int part[256];
    const int CH = 63;
    int t = threadIdx.x;
    int s = 0;
    for (int j = 0; j < CH; ++j) {
        int i = t * CH + j;
        if (i < B_ * N_) s += counts[i];
    }
    part[t] = s;
    __syncthreads();
    if (t == 0) {
        int run = 0;
        for (int i = 0; i < 256; ++i) { int v = part[i]; part[i] = run; run += v; }
    }
    __syncthreads();
    int run = part[t];
    for (int j = 0; j < CH; ++j) {
        int i = t * CH + j;
        if (i < B_ * N_) { offsets[i] = run; run += counts[i]; }
    }
    if (t == 255) offsets[B_ * N_] = run;
}

__global__ void k_build(const int* __restrict__ endi,
                        const int* __restrict__ seg,
                        const int* __restrict__ offsets,
                        int* __restrict__ cursor, int* __restrict__ nodelist) {
    int i = blockIdx.x * blockDim.x + threadIdx.x;
    if (i >= B_ * L_ * K_) return;
    if (!endi[i]) return;
    int b = i / (L_ * K_);
    int lk = i - b * (L_ * K_);
    int n = seg[i];
    int pos = atomicAdd(&cursor[b * N_ + n], 1);
    nodelist[offsets[b * N_ + n] + pos] = lk;
}

// ---------------------------------------------------------------------------
// Level l>=1: best-measured configuration (r14/r16, 308.8us end-to-end,
// reproduced twice).  BYTE-IDENTICAL to round 16 — do not touch.
// Z_l = diag(alpha)*(Z_{l-1}[gidx] @ W^T) + H_l.
// 512 thr = 8 waves (4M x 2N), wave tile 32x80 = 2x5 frags, acc=40 VGPR.
// gll staging with source-side XOR swizzle (bank-conflict-free, r12: 2.5e7->0),
// 4-buffer depth-2 pipeline, issue-first order: issue gll(s+2) -> wait
// vm(2 batches) -> barrier -> ds_read -> MFMA.
__global__ __launch_bounds__(512, 4)
void k_level_gemm(const float* __restrict__ attn,
                  const int* __restrict__ seg, const int* __restrict__ parent,
                  const unsigned short* __restrict__ featsbf,
                  const unsigned short* __restrict__ wb,
                  const unsigned short* __restrict__ zprev,
                  unsigned short* __restrict__ zcur,
                  int l, int prevRows, int useps) {
    __shared__ unsigned short AsF[4 * 128 * 32];   // 4 bufs x 8KB
    __shared__ unsigned short BsF[4 * 160 * 32];   // 4 bufs x 10KB
    __shared__ int gidx_s[128], seg_s[128];
    __shared__ float alpha_s[128];

    int tid = threadIdx.x;
    int id = blockIdx.x;                 // 768 = 8 batches x 32 M x 3 N
    int b = id & 7;
    int within = id >> 3;
    int mb = within / 3, nb = within - mb * 3;
    int k0 = mb * 128, d0 = nb * 160;

    if (tid < 128) {
        int base = (b * L_ + l) * K_;
        int p = parent[base + k0 + tid];
        int sk = seg[base + k0 + tid];
        int ps = seg[base - K_ + p];
        gidx_s[tid] = useps ? ps : p;
        seg_s[tid] = sk;
        alpha_s[tid] = attn[((size_t)b * N_ + ps) * N_ + sk];
    }
    __syncthreads();

    const unsigned short* zb = zprev + (size_t)b * prevRows * D_;
    int w = tid >> 6, lane = tid & 63;
    int l4 = lane >> 2, c4 = lane & 3;

    // A: wave w stages chunk w (rows w*16..w*16+15); 1 gll/batch
    const unsigned short* srcA;
    int dA;
    {
        int r = w * 16 + l4;
        int sc = c4 ^ ((r >> 1) & 3);          // source-side swizzle
        srcA = zb + (size_t)gidx_s[r] * D_ + sc * 8;
        dA = w * 512;
    }
    // B: wave w stages chunk w; waves 0,1 additionally chunks 8,9
    int nB = (w < 2) ? 2 : 1;
    const unsigned short* srcB[2];
    int dB[2];
#pragma unroll
    for (int t = 0; t < 2; ++t) {
        int jb = (t == 0) ? w : (8 + w);
        if (jb > 9) jb = 9;                    // unused (never issued)
        int r = jb * 16 + l4;
        int sc = c4 ^ ((r >> 1) & 3);
        srcB[t] = wb + (size_t)(d0 + r) * D_ + sc * 8;
        dB[t] = jb * 512;
    }

    int waveM = w >> 1, waveN = w & 1;         // 4M x 2N
    int lr = lane & 15, kg = lane >> 4;
    int afo[2], bfo[5];
#pragma unroll
    for (int fm = 0; fm < 2; ++fm) {
        int r = waveM * 32 + fm * 16 + lr;
        afo[fm] = r * 32 + (kg ^ ((r >> 1) & 3)) * 8;   // inverse swizzle
    }
#pragma unroll
    for (int fn = 0; fn < 5; ++fn) {
        int r = waveN * 80 + fn * 16 + lr;
        bfo[fn] = r * 32 + (kg ^ ((r >> 1) & 3)) * 8;
    }

    f32x4 acc[2][5];
#pragma unroll
    for (int fm = 0; fm < 2; ++fm)
#pragma unroll
        for (int fn = 0; fn < 5; ++fn) acc[fm][fn] = (f32x4)0.f;

    // prologue: issue batches 0,1 into bufs 0,1
#pragma unroll
    for (int q = 0; q < 2; ++q) {
        GLL16(srcA + q * 32, &AsF[q * 4096 + dA]);
#pragma unroll
        for (int t = 0; t < 2; ++t)
            if (t < nB) GLL16(srcB[t] + q * 32, &BsF[q * 5120 + dB[t]]);
    }

#pragma unroll
    for (int s = 0; s < 15; ++s) {
        // issue batch s+2 first (buf (s+2)&3: readers were 2 barriers back)
        if (s + 2 <= 14) {
            int q2 = (s + 2) & 3;
            GLL16(srcA + (s + 2) * 32, &AsF[q2 * 4096 + dA]);
#pragma unroll
            for (int t = 0; t < 2; ++t)
                if (t < nB) GLL16(srcB[t] + (s + 2) * 32, &BsF[q2 * 5120 + dB[t]]);
        }
        // wait: batch s landed, batches s+1,s+2 stay in flight
        if (s <= 12)      { if (w < 2) vm6(); else vm4(); }
        else if (s == 13) { if (w < 2) vm3(); else vm2(); }
        else              vm0();
        __builtin_amdgcn_s_barrier();

        int q = s & 3;
        bf16x8 af[2], bfr[5];
#pragma unroll
        for (int fm = 0; fm < 2; ++fm)
            af[fm] = *(const bf16x8*)&AsF[q * 4096 + afo[fm]];
#pragma unroll
        for (int fn = 0; fn < 5; ++fn)
            bfr[fn] = *(const bf16x8*)&BsF[q * 5120 + bfo[fn]];
#pragma unroll
        for (int fm = 0; fm < 2; ++fm)
#pragma unroll
            for (int fn = 0; fn < 5; ++fn)
                acc[fm][fn] = __builtin_amdgcn_mfma_f32_16x16x32_bf16(
                    af[fm], bfr[fn], acc[fm][fn], 0, 0, 0);
    }

    // epilogue: C layout col=lane&15, row=(lane>>4)*4+j
#pragma unroll
    for (int fm = 0; fm < 2; ++fm) {
#pragma unroll
        for (int j = 0; j < 4; ++j) {
            int rl = waveM * 32 + fm * 16 + kg * 4 + j;
            float al = alpha_s[rl];
            int sk = seg_s[rl];
            const unsigned short* hrow = featsbf + ((size_t)b * N_ + sk) * D_;
            unsigned short* zrow = zcur + ((size_t)b * K_ + k0 + rl) * D_;
#pragma unroll
            for (int fn = 0; fn < 5; ++fn) {
                int c = d0 + waveN * 80 + fn * 16 + lr;
                zrow[c] = f2bf(al * acc[fm][fn][j] + bf2f(hrow[c]));
            }
        }
    }
}

// Fused gather-reduce + mean + predictor + mask.  128 threads (2 waves) per
// (b,n): one 4-elem chunk per thread (c4 = tid, 120 active) -> half the
// serial loads per node row vs the 64-thread version, 2x TLP.
__global__ __launch_bounds__(128)
void k_final_gather(const unsigned short* __restrict__ featsbf,
                    const unsigned short* __restrict__ zall,
                    const int* __restrict__ offsets,
                    const int* __restrict__ nodelist,
                    const float* __restrict__ Wpred,
                    const float* __restrict__ bpred, float* __restrict__ out) {
    __shared__ float wpart[2][T1_];
    int bn = blockIdx.x;
    int b = bn / N_;
    int s0 = offsets[bn], s1 = offsets[bn + 1];
    int cnt = s1 - s0;
    int tid = threadIdx.x;
    int c4 = tid;                       // 0..119 valid (D/4 = 120)
    bool act = (c4 < D_ / 4);

    float a0 = 0.f, a1 = 0.f, a2 = 0.f, a3 = 0.f;
    const unsigned short* ownrow = featsbf + (size_t)bn * D_;

    for (int s = s0; s < s1; ++s) {
        int e = nodelist[s];
        int l = e >> 12, k = e & (K_ - 1);
        const unsigned short* row =
            (l == 0) ? ownrow
                     : zall + (((size_t)(l - 1) * B_ + b) * K_ + k) * D_;
        if (act) {
            ushort4 u = *(const ushort4*)(row + c4 * 4);
            a0 += bf2f(u.x);
            a1 += bf2f(u.y);
            a2 += bf2f(u.z);
            a3 += bf2f(u.w);
        }
    }

    float inv = 1.f / (float)(cnt > 1 ? cnt : 1);
    float m0 = a0 * inv, m1 = a1 * inv, m2 = a2 * inv, m3 = a3 * inv;

    float* outz = out + (size_t)B_ * N_ * T1_ + (size_t)bn * D_;
    if (act) {
        float4 v;
        v.x = m0; v.y = m1; v.z = m2; v.w = m3;
        *(float4*)(outz + c4 * 4) = v;
    }

    float part[T1_] = {0, 0, 0, 0, 0, 0};
    if (act) {
#pragma unroll
        for (int t = 0; t < T1_; ++t) {
            const float* wp = Wpred + t * D_ + c4 * 4;
            part[t] = m0 * wp[0] + m1 * wp[1] + m2 * wp[2] + m3 * wp[3];
        }
    }
#pragma unroll
    for (int t = 0; t < T1_; ++t)
        for (int off = 32; off; off >>= 1)
            part[t] += __shfl_down(part[t], off);
    int w = tid >> 6, lane = tid & 63;
    if (lane == 0) {
#pragma unroll
        for (int t = 0; t < T1_; ++t) wpart[w][t] = part[t];
    }
    __syncthreads();
    if (tid == 0) {
#pragma unroll
        for (int t = 0; t < T1_; ++t)
            out[(size_t)bn * T1_ + t] =
                (cnt > 0) ? (wpart[0][t] + wpart[1][t] + bpred[t]) : 0.f;
        out[(size_t)B_ * N_ * T1_ + (size_t)B_ * N_ * D_ + bn] =
            (cnt > 0) ? 1.f : 0.f;
    }
}

// ======================= fallback (atomic) path kernels =====================
__global__ void k_zero(float* __restrict__ sums, int* __restrict__ counts) {
    int stride = gridDim.x * blockDim.x;
    int i0 = blockIdx.x * blockDim.x + threadIdx.x;
    for (int i = i0; i < B_ * N_ * D_; i += stride) sums[i] = 0.f;
    for (int i = i0; i < B_ * N_; i += stride) counts[i] = 0;
}

__global__ __launch_bounds__(128)
void k_level0_at(const float* __restrict__ feats, const int* __restrict__ seg,
                 const int* __restrict__ endi, unsigned short* __restrict__ z0,
                 float* __restrict__ sums) {
    int bk = blockIdx.x;
    int b = bk >> 12;
    int k = bk & (K_ - 1);
    int sidx = (b * L_ + 0) * K_ + k;
    int n = seg[sidx];
    int e = endi[sidx];
    const float* src = feats + ((size_t)b * N_ + n) * D_;
    unsigned short* dst = z0 + ((size_t)b * K_ + k) * D_;
    float* sm = sums + ((size_t)b * N_ + n) * D_;
    int t = threadIdx.x;
    if (t < D_ / 4) {
        float4 v = *(const float4*)(src + t * 4);
        ushort4 o;
        o.x = f2bf(v.x); o.y = f2bf(v.y); o.z = f2bf(v.z); o.w = f2bf(v.w);
        *(ushort4*)(dst + t * 4) = o;
        if (e) {
            atomicAdd(&sm[t * 4 + 0], v.x);
            atomicAdd(&sm[t * 4 + 1], v.y);
            atomicAdd(&sm[t * 4 + 2], v.z);
            atomicAdd(&sm[t * 4 + 3], v.w);
        }
    }
}

__global__ __launch_bounds__(256)
void k_level_mfma_at(const float* __restrict__ feats,
                     const float* __restrict__ attn,
                     const int* __restrict__ seg, const int* __restrict__ parent,
                     const int* __restrict__ endi,
                     const unsigned short* __restrict__ wb,
                     const unsigned short* __restrict__ zprev,
                     unsigned short* __restrict__ zcur,
                     float* __restrict__ sums, int l, int storez) {
    __shared__ int par_s[BM], seg_s[BM], end_s[BM];
    __shared__ float alpha_s[BM];
    int b = blockIdx.z;
    int k0 = blockIdx.x * BM;
    int d0 = blockIdx.y * BN;
    int tid = threadIdx.x;
    if (tid < BM) {
        int base = (b * L_ + l) * K_;
        int p = parent[base + k0 + tid];
        int sk = seg[base + k0 + tid];
        int ps = seg[base - K_ + p];
        par_s[tid] = p; seg_s[tid] = sk;
        end_s[tid] = endi[base + k0 + tid];
        alpha_s[tid] = attn[((size_t)b * N_ + ps) * N_ + sk];
    }
    __syncthreads();
    int wave = tid >> 6, lane = tid & 63;
    int wr0 = (wave >> 1) * 32, wc0 = (wave & 1) * 48;
    int laneRow = lane & 15, laneK = (lane >> 4) * 8;
    const unsigned short* zb = zprev + (size_t)b * K_ * D_;
    const unsigned short* arow[2];
#pragma unroll
    for (int mi = 0; mi < 2; ++mi)
        arow[mi] = zb + (size_t)par_s[wr0 + mi * 16 + laneRow] * D_ + laneK;
    const unsigned short* brow[3];
#pragma unroll
    for (int ni = 0; ni < 3; ++ni)
        brow[ni] = wb + (size_t)(d0 + wc0 + ni * 16 + laneRow) * D_ + laneK;
    f32x4 acc[2][3];
#pragma unroll
    for (int mi = 0; mi < 2; ++mi)
#pragma unroll
        for (int ni = 0; ni < 3; ++ni) acc[mi][ni] = (f32x4)0.f;
    bf16x8 af[2], bfr[3];
#pragma unroll
    for (int mi = 0; mi < 2; ++mi) af[mi] = *(const bf16x8*)(arow[mi]);
#pragma unroll
    for (int ni = 0; ni < 3; ++ni) bfr[ni] = *(const bf16x8*)(brow[ni]);
#pragma unroll
    for (int e0 = 0; e0 < D_; e0 += 32) {
        bf16x8 an[2], bn[3];
        if (e0 + 32 < D_) {
#pragma unroll
            for (int mi = 0; mi < 2; ++mi) an[mi] = *(const bf16x8*)(arow[mi] + e0 + 32);
#pragma unroll
            for (int ni = 0; ni < 3; ++ni) bn[ni] = *(const bf16x8*)(brow[ni] + e0 + 32);
        }
#pragma unroll
        for (int mi = 0; mi < 2; ++mi)
#pragma unroll
            for (int ni = 0; ni < 3; ++ni)
                acc[mi][ni] = __builtin_amdgcn_mfma_f32_16x16x32_bf16(
                    af[mi], bfr[ni], acc[mi][ni], 0, 0, 0);
        if (e0 + 32 < D_) {
#pragma unroll
            for (int mi = 0; mi < 2; ++mi) af[mi] = an[mi];
#pragma unroll
            for (int ni = 0; ni < 3; ++ni) bfr[ni] = bn[ni];
        }
    }
#pragma unroll
    for (int mi = 0; mi < 2; ++mi) {
#pragma unroll
        for (int j = 0; j < 4; ++j) {
            int rl = wr0 + mi * 16 + (lane >> 4) * 4 + j;
            int k = k0 + rl;
            float al = alpha_s[rl];
            int sk = seg_s[rl];
            int en = end_s[rl];
            const float* hrow = feats + ((size_t)b * N_ + sk) * D_;
            unsigned short* zrow = zcur + ((size_t)b * K_ + k) * D_;
            float* srow = sums + ((size_t)b * N_ + sk) * D_;
#pragma unroll
            for (int ni = 0; ni < 3; ++ni) {
                int c = d0 + wc0 + ni * 16 + (lane & 15);
                float v = al * acc[mi][ni][j] + hrow[c];
                if (storez) zrow[c] = f2bf(v);
                if (en) atomicAdd(&srow[c], v);
            }
        }
    }
}

__global__ __launch_bounds__(64)
void k_final_at(const float* __restrict__ sums, const int* __restrict__ counts,
                const float* __restrict__ Wpred, const float* __restrict__ bpred,
                float* __restrict__ out) {
    int bn = blockIdx.x;
    int cnt = counts[bn];
    float inv = 1.f / (float)(cnt > 1 ? cnt : 1);
    int lane = threadIdx.x;
    const float* srow = sums + (size_t)bn * D_;
    float* zout = out + (size_t)B_ * N_ * T1_ + (size_t)bn * D_;
    float part[T1_] = {0, 0, 0, 0, 0, 0};
    for (int d = lane; d < D_; d += 64) {
        float mval = srow[d] * inv;
        zout[d] = mval;
#pragma unroll
        for (int t = 0; t < T1_; ++t) part[t] += mval * Wpred[t * D_ + d];
    }
#pragma unroll
    for (int t = 0; t < T1_; ++t) {
        float v = part[t];
        for (int off = 32; off; off >>= 1) v += __shfl_down(v, off);
        if (lane == 0)
            out[(size_t)bn * T1_ + t] = (cnt > 0) ? (v + bpred[t]) : 0.f;
    }
    if (lane == 0)
        out[(size_t)B_ * N_ * T1_ + (size_t)B_ * N_ * D_ + bn] =
            (cnt > 0) ? 1.f : 0.f;
}

// ===========================================================================
extern "C" void kernel_launch(void* const* d_in, const int* in_sizes, int n_in,
                              void* d_out, int out_size, void* d_ws,
                              size_t ws_size, hipStream_t stream) {
    const float* feats = (const float*)d_in[0];
    const float* attn  = (const float*)d_in[1];
    const int*   seg   = (const int*)d_in[2];
    const int*   par   = (const int*)d_in[3];
    const unsigned char* isend_raw = (const unsigned char*)d_in[4];
    const float* Wproj = (const float*)d_in[5];
    const float* Wpred = (const float*)d_in[6];
    const float* bpred = (const float*)d_in[7];

    char* p = (char*)d_ws;
    auto carve = [&p](size_t bytes) -> char* {
        char* r = p;
        p += (bytes + 255) & ~(size_t)255;
        return r;
    };

    size_t need = 0;
    {
        size_t q = 0;
        auto sz = [&q](size_t b) { q += (b + 255) & ~(size_t)255; };
        sz(B_ * N_ * 4);
        sz(B_ * N_ * 4);
        sz((B_ * N_ + 1) * 4);
        sz((size_t)B_ * L_ * K_ * 4);
        sz(16);
        sz((size_t)B_ * L_ * K_ * 4);
        sz((size_t)B_ * N_ * D_ * 2);
        sz((size_t)D_ * D_ * 2);
        sz((size_t)(L_ - 1) * B_ * K_ * D_ * 2);
        need = q;
    }

    if (ws_size >= need) {
        int* counts = (int*)carve(B_ * N_ * 4);
        int* cursor = (int*)carve(B_ * N_ * 4);
        int* offsets = (int*)carve((B_ * N_ + 1) * 4);
        int* endi = (int*)carve((size_t)B_ * L_ * K_ * 4);
        int* flag = (int*)carve(16);
        int* nodelist = (int*)carve((size_t)B_ * L_ * K_ * 4);
        unsigned short* featsbf = (unsigned short*)carve((size_t)B_ * N_ * D_ * 2);
        unsigned short* wbf = (unsigned short*)carve((size_t)D_ * D_ * 2);
        unsigned short* zall =
            (unsigned short*)carve((size_t)(L_ - 1) * B_ * K_ * D_ * 2);

        k_prep<<<(B_ * N_ + 255) / 256, 256, 0, stream>>>(isend_raw, flag,
                                                          counts, cursor);
        k_conv<<<(B_ * N_ * D_ / 4 + 255) / 256, 256, 0, stream>>>(
            Wproj, wbf, feats, featsbf);
        k_endcounts<<<(B_ * L_ * K_ + 255) / 256, 256, 0, stream>>>(
            isend_raw, flag, seg, endi, counts);
        k_scan<<<1, 256, 0, stream>>>(counts, offsets);
        k_build<<<(B_ * L_ * K_ + 255) / 256, 256, 0, stream>>>(
            endi, seg, offsets, cursor, nodelist);

        for (int l = 1; l < L_; ++l) {
            const unsigned short* zp =
                (l == 1) ? featsbf : zall + (size_t)(l - 2) * B_ * K_ * D_;
            unsigned short* zc = zall + (size_t)(l - 1) * B_ * K_ * D_;
            k_level_gemm<<<768, 512, 0, stream>>>(
                attn, seg, par, featsbf, wbf, zp, zc, l,
                (l == 1) ? N_ : K_, (l == 1) ? 1 : 0);
        }

        k_final_gather<<<B_ * N_, 128, 0, stream>>>(
            featsbf, zall, offsets, nodelist, Wpred, bpred, (float*)d_out);
    } else {
        // fallback: round-3 atomic path
        float* sums = (float*)carve((size_t)B_ * N_ * D_ * 4);
        int* counts = (int*)carve(B_ * N_ * 4);
        int* endi = (int*)carve((size_t)B_ * L_ * K_ * 4);
        int* flag = (int*)carve(16);
        unsigned short* z0bf = (unsigned short*)carve((size_t)B_ * K_ * D_ * 2);
        unsigned short* z1bf = (unsigned short*)carve((size_t)B_ * K_ * D_ * 2);
        unsigned short* wbf = (unsigned short*)carve((size_t)D_ * D_ * 2);

        k_prep<<<(B_ * N_ + 255) / 256, 256, 0, stream>>>(isend_raw, flag,
                                                          counts, counts);
        k_zero<<<1024, 256, 0, stream>>>(sums, counts);
        k_conv<<<(B_ * N_ * D_ / 4 + 255) / 256, 256, 0, stream>>>(
            Wproj, wbf, feats, (unsigned short*)z0bf /*scratch reuse*/);
        k_endcounts<<<(B_ * L_ * K_ + 255) / 256, 256, 0, stream>>>(
            isend_raw, flag, seg, endi, counts);
        k_level0_at<<<B_ * K_, 128, 0, stream>>>(feats, seg, endi, z0bf, sums);
        unsigned short* zp = z0bf;
        unsigned short* zc = z1bf;
        for (int l = 1; l < L_; ++l) {
            k_level_mfma_at<<<dim3(K_ / BM, D_ / BN, B_), 256, 0, stream>>>(
                feats, attn, seg, par, endi, wbf, zp, zc, sums, l,
                (l < L_ - 1) ? 1 : 0);
            unsigned short* t = zp; zp = zc; zc = t;
        }
        k_final_at<<<B_ * N_, 64, 0, stream>>>(sums, counts, Wpred, bpred,
                                               (float*)d_out);
    }
}